// Round 11
// baseline (52.879 us; speedup 1.0000x reference)
//
#include <hip/hip_runtime.h>

typedef float f32x4 __attribute__((ext_vector_type(4)));
typedef __bf16 bf16x8 __attribute__((ext_vector_type(8)));

#define S 32
#define DTC 0.3f

__device__ __forceinline__ float frcp(float x) { return __builtin_amdgcn_rcpf(x); }

// tanh(x) = 1 - 2/(e^{2x}+1); exact saturation via exp->inf/0.
__device__ __forceinline__ float ftanh(float x) {
    float e = __expf(2.0f * x);
    return 1.0f - 2.0f * frcp(e + 1.0f);
}

// jax.nn.gelu(approximate=True)
__device__ __forceinline__ float fgelu(float x) {
    float t = ftanh(0.7978845608028654f * x * (1.0f + 0.044715f * x * x));
    return 0.5f * x * (1.0f + t);
}

// wave-local LDS ordering: drain own DS ops; block compiler reordering.
#define WAVE_LDS_FENCE() asm volatile("s_waitcnt lgkmcnt(0)" ::: "memory")
#define REORDER_FENCE()  asm volatile("" ::: "memory")

union ABFrag { bf16x8 v; };

// load 8 consecutive floats (16B-aligned) as two float4
__device__ __forceinline__ void load_row8(const float* p, float out[8]) {
    const float4* q = reinterpret_cast<const float4*>(p);
    float4 a = q[0], b = q[1];
    out[0]=a.x; out[1]=a.y; out[2]=a.z; out[3]=a.w;
    out[4]=b.x; out[5]=b.y; out[6]=b.z; out[7]=b.w;
}

__device__ __forceinline__ ABFrag pack8(const float f[8]) {
    ABFrag r;
    #pragma unroll
    for (int e = 0; e < 8; e++) r.v[e] = (__bf16)f[e];   // compiler: v_cvt_pk_bf16_f32
    return r;
}

// B-frag: W row-major (K x 32); k = kbase + e (kbase includes 8*lg), fixed col
__device__ __forceinline__ ABFrag load_w(const float* W, int kbase, int col) {
    ABFrag r;
    #pragma unroll
    for (int e = 0; e < 8; e++) r.v[e] = (__bf16)W[(kbase + e) * S + col];
    return r;
}

#define MFMA(a, b, c) __builtin_amdgcn_mfma_f32_16x16x32_bf16((a), (b), (c), 0, 0, 0)

// C-layout (2 n-tiles x 4 rows, fp32) -> A-frag via per-WAVE LDS bounce.
#define BOUNCE(dstFrag, srcC, scale)                                            \
    {                                                                           \
        _Pragma("unroll")                                                       \
        for (int nt_ = 0; nt_ < 2; nt_++)                                       \
            _Pragma("unroll")                                                   \
            for (int r_ = 0; r_ < 4; r_++)                                      \
                lbuf[wid][(4*lg + r_)*40 + lr + 16*nt_] =                       \
                    (__bf16)((srcC)[nt_][r_] * (scale));                        \
        WAVE_LDS_FENCE();                                                       \
        (dstFrag).v = *(const bf16x8*)&lbuf[wid][lr*40 + 8*lg];                 \
        REORDER_FENCE();                                                        \
    }

__global__ __launch_bounds__(256, 4) void moe_kernel(
    const float* __restrict__ cs,  const float* __restrict__ nb,
    const float* __restrict__ Wl,  const float* __restrict__ bl,
    const float* __restrict__ Wm,  const float* __restrict__ bm,
    const float* __restrict__ Wu,  const float* __restrict__ bu,
    const float* __restrict__ Wc,  const float* __restrict__ bc,
    const float* __restrict__ Wd,  const float* __restrict__ bd,
    const float* __restrict__ lng, const float* __restrict__ lnb,
    const float* __restrict__ gW1, const float* __restrict__ gb1,
    const float* __restrict__ gW2, const float* __restrict__ gb2,
    float* __restrict__ out, int B)
{
    __shared__ __align__(16) __bf16 lbuf[4][16 * 40]; // per-wave bounce

    const int tid = threadIdx.x;
    const int wid = tid >> 6, lane = tid & 63;
    const int lr = lane & 15, lg = lane >> 4;
    const int b0 = (blockIdx.x * 4 + wid) * 16;
    if (b0 >= B) return;
    const int wcol0 = lr;          // n-tile 0 col
    const int wcol1 = lr + 16;     // n-tile 1 col
    const int wk = 8 * lg;         // k-base within a 32-K tile

    // ---- early weights only (WlB used now; WmB/WuB in func phase): 40 VGPRs
    ABFrag WlB[2][2], WuB[2][2], WmB[2];
    #pragma unroll
    for (int nt = 0; nt < 2; nt++) {
        const int col = nt ? wcol1 : wcol0;
        #pragma unroll
        for (int kt = 0; kt < 2; kt++) {
            WlB[kt][nt] = load_w(Wl, kt * 32 + wk, col);
            WuB[kt][nt] = load_w(Wu, kt * 32 + wk, col);
        }
        WmB[nt] = load_w(Wm, wk, col);
    }
    // biases in C-layout (per n-tile, col = lr+16nt, same for all 4 rows)
    const float blc[2] = { bl[lr], bl[lr + 16] };
    const float bmc[2] = { bm[lr], bm[lr + 16] };
    const float buc[2] = { bu[lr], bu[lr + 16] };

    // ---- x: A-layout (keep fp32 for LN) and C-layout (residuals)
    float xf[8];
    load_row8(cs + (size_t)(b0 + lr) * S + 8 * lg, xf);
    ABFrag xA = pack8(xf);
    float xC[2][4];
    #pragma unroll
    for (int nt = 0; nt < 2; nt++)
        #pragma unroll
        for (int r = 0; r < 4; r++)
            xC[nt][r] = cs[(size_t)(b0 + 4 * lg + r) * S + lr + 16 * nt];

    float act[8];
    #pragma unroll
    for (int e = 0; e < 8; e++) act[e] = 0.0f;

    // ---- local rows 0..2 -> loc (fp32 avg) ; act accum
    float locf[8];
    #pragma unroll
    for (int e = 0; e < 8; e++) locf[e] = 0.0f;
    #pragma unroll
    for (int k = 0; k < 3; k++) {
        float rf[8];
        load_row8(nb + ((size_t)(b0 + lr) * 26 + k) * S + 8 * lg, rf);
        #pragma unroll
        for (int e = 0; e < 8; e++) { locf[e] += rf[e]; act[e] += fabsf(rf[e]); }
    }
    #pragma unroll
    for (int e = 0; e < 8; e++) locf[e] *= (1.0f / 3.0f);
    ABFrag locA = pack8(locf);

    // ---- yl = x + tanh([x,loc]@Wl + bl)   (C-layout; WlB dies here)
    float ylC[2][4];
    #pragma unroll
    for (int nt = 0; nt < 2; nt++) {
        f32x4 acc = { blc[nt], blc[nt], blc[nt], blc[nt] };
        acc = MFMA(xA.v,   WlB[0][nt].v, acc);
        acc = MFMA(locA.v, WlB[1][nt].v, acc);
        #pragma unroll
        for (int r = 0; r < 4; r++) ylC[nt][r] = xC[nt][r] + ftanh(acc[r]);
    }

    // ---- func rows 3..16: agg += gelu(row@Wm + bm)   (C-layout accum)
    float aggC[2][4];
    #pragma unroll
    for (int nt = 0; nt < 2; nt++)
        #pragma unroll
        for (int r = 0; r < 4; r++) aggC[nt][r] = 0.0f;
    #pragma unroll 2
    for (int k = 0; k < 14; k++) {
        float rf[8];
        load_row8(nb + ((size_t)(b0 + lr) * 26 + 3 + k) * S + 8 * lg, rf);
        #pragma unroll
        for (int e = 0; e < 8; e++) act[e] += fabsf(rf[e]);
        ABFrag a = pack8(rf);
        #pragma unroll
        for (int nt = 0; nt < 2; nt++) {
            f32x4 am = { bmc[nt], bmc[nt], bmc[nt], bmc[nt] };
            am = MFMA(a.v, WmB[nt].v, am);
            #pragma unroll
            for (int r = 0; r < 4; r++) aggC[nt][r] += fgelu(am[r]);
        }
    }

    // ---- WcB loads issue here; latency hides under the agg bounce
    ABFrag WcB[2];
    WcB[0] = load_w(Wc, wk, wcol0);
    WcB[1] = load_w(Wc, wk, wcol1);
    const float bcc[2] = { bc[lr], bc[lr + 16] };

    // ---- agg/14 -> A-frag (transpose bounce)
    ABFrag aggA;
    BOUNCE(aggA, aggC, (1.0f / 14.0f));

    // ---- h = x + tanh([x,agg]@Wu + bu); yf = h + DT*tanh(h@Wc + bc)
    float hC[2][4], yfC[2][4];
    #pragma unroll
    for (int nt = 0; nt < 2; nt++) {
        f32x4 acc = { buc[nt], buc[nt], buc[nt], buc[nt] };
        acc = MFMA(xA.v,   WuB[0][nt].v, acc);
        acc = MFMA(aggA.v, WuB[1][nt].v, acc);
        #pragma unroll
        for (int r = 0; r < 4; r++) hC[nt][r] = xC[nt][r] + ftanh(acc[r]);
    }
    ABFrag hA;
    BOUNCE(hA, hC, 1.0f);
    #pragma unroll
    for (int nt = 0; nt < 2; nt++) {
        f32x4 acc = { bcc[nt], bcc[nt], bcc[nt], bcc[nt] };
        acc = MFMA(hA.v, WcB[nt].v, acc);
        #pragma unroll
        for (int r = 0; r < 4; r++) yfC[nt][r] = hC[nt][r] + DTC * ftanh(acc[r]);
    }

    // ---- WdB loads issue here; latency hides under dist + gate (~1500 cy)
    ABFrag WdB[2][2];
    #pragma unroll
    for (int nt = 0; nt < 2; nt++) {
        const int col = nt ? wcol1 : wcol0;
        WdB[0][nt] = load_w(Wd, wk, col);
        WdB[1][nt] = load_w(Wd, 32 + wk, col);
    }
    const float bdc[2] = { bd[lr], bd[lr + 16] };

    // ---- dist rows 17..25 -> fp32 avg ; act accum
    float distf[8];
    #pragma unroll
    for (int e = 0; e < 8; e++) distf[e] = 0.0f;
    #pragma unroll 3
    for (int k = 0; k < 9; k++) {
        float rf[8];
        load_row8(nb + ((size_t)(b0 + lr) * 26 + 17 + k) * S + 8 * lg, rf);
        #pragma unroll
        for (int e = 0; e < 8; e++) { distf[e] += rf[e]; act[e] += fabsf(rf[e]); }
    }
    #pragma unroll
    for (int e = 0; e < 8; e++) distf[e] *= (1.0f / 9.0f);
    ABFrag distA = pack8(distf);

    // ---- gate (fp32, wave reductions over lg groups; vectorized table loads)
    float gate0, gate1, gate2;
    {
        float s = 0.0f;
        #pragma unroll
        for (int e = 0; e < 8; e++) s += xf[e];
        s += __shfl_xor(s, 16); s += __shfl_xor(s, 32);
        const float mu = s * (1.0f / S);
        float v = 0.0f;
        #pragma unroll
        for (int e = 0; e < 8; e++) { float d = xf[e] - mu; v += d * d; }
        v += __shfl_xor(v, 16); v += __shfl_xor(v, 32);
        const float rstd = rsqrtf(v * (1.0f / S) + 1e-5f);

        float lngv[8], lnbv[8];
        load_row8(lng + 8 * lg, lngv);
        load_row8(lnb + 8 * lg, lnbv);

        float g1v[8];
        #pragma unroll
        for (int u = 0; u < 8; u++) g1v[u] = 0.0f;
        #pragma unroll
        for (int e = 0; e < 8; e++) {
            const int i = 8 * lg + e;
            const float a  = (xf[e] - mu) * rstd * lngv[e] + lnbv[e];
            const float ac = act[e] * (1.0f / 26.0f);
            float w1[8], w2[8];
            load_row8(gW1 + i * 8, w1);          // row i of gW1 (8 floats)
            load_row8(gW1 + (S + i) * 8, w2);    // row S+i
            #pragma unroll
            for (int u = 0; u < 8; u++) g1v[u] += a * w1[u] + ac * w2[u];
        }
        float l0 = gb2[0], l1 = gb2[1], l2 = gb2[2];
        #pragma unroll
        for (int u = 0; u < 8; u++) {
            float gt = g1v[u];
            gt += __shfl_xor(gt, 16); gt += __shfl_xor(gt, 32);
            const float g = fgelu(gt + gb1[u]);
            l0 += g * gW2[u * 3 + 0];
            l1 += g * gW2[u * 3 + 1];
            l2 += g * gW2[u * 3 + 2];
        }
        const float mx = fmaxf(l0, fmaxf(l1, l2));
        const float e0 = __expf(l0 - mx), e1 = __expf(l1 - mx), e2 = __expf(l2 - mx);
        const float rs = frcp(e0 + e1 + e2);
        gate0 = e0 * rs; gate1 = e1 * rs; gate2 = e2 * rs;
    }

    // ---- CNF: 3 steps; xt in C-layout + A-frag (re-bounced per step)
    float xtC[2][4];
    #pragma unroll
    for (int nt = 0; nt < 2; nt++)
        #pragma unroll
        for (int r = 0; r < 4; r++) xtC[nt][r] = xC[nt][r];
    ABFrag xtA = xA;
    #pragma unroll 1
    for (int it = 0; it < 3; it++) {
        #pragma unroll
        for (int nt = 0; nt < 2; nt++) {
            f32x4 acc = { bdc[nt], bdc[nt], bdc[nt], bdc[nt] };
            acc = MFMA(xtA.v,  WdB[0][nt].v, acc);
            acc = MFMA(distA.v, WdB[1][nt].v, acc);
            #pragma unroll
            for (int r = 0; r < 4; r++) xtC[nt][r] += DTC * ftanh(acc[r]);
        }
        if (it < 2) { BOUNCE(xtA, xtC, 1.0f); }
    }

    // ---- combine + store (C-layout rows coalesced); gates via wave shuffle:
    // gates for batch row i live in lane i (i<16). row = 4*lg + r.
    #pragma unroll
    for (int nt = 0; nt < 2; nt++)
        #pragma unroll
        for (int r = 0; r < 4; r++) {
            const int srcl = 4 * lg + r;
            const float g0 = __shfl(gate0, srcl);
            const float g1 = __shfl(gate1, srcl);
            const float g2 = __shfl(gate2, srcl);
            out[(size_t)(b0 + 4 * lg + r) * S + lr + 16 * nt] =
                g0 * ylC[nt][r] + g1 * yfC[nt][r] + g2 * xtC[nt][r];
        }
    if (lg == 0) {
        float* gp = out + (size_t)B * S + (size_t)(b0 + lr) * 3;
        gp[0] = gate0; gp[1] = gate1; gp[2] = gate2;
    }
}

extern "C" void kernel_launch(void* const* d_in, const int* in_sizes, int n_in,
                              void* d_out, int out_size, void* d_ws, size_t ws_size,
                              hipStream_t stream)
{
    const int B = in_sizes[0] / S;
    dim3 block(256);
    dim3 grid((B + 63) / 64);   // 64 batch per block (4 waves x 16)
    hipLaunchKernelGGL(moe_kernel, grid, block, 0, stream,
        (const float*)d_in[0],  (const float*)d_in[1],
        (const float*)d_in[2],  (const float*)d_in[3],
        (const float*)d_in[4],  (const float*)d_in[5],
        (const float*)d_in[6],  (const float*)d_in[7],
        (const float*)d_in[8],  (const float*)d_in[9],
        (const float*)d_in[10], (const float*)d_in[11],
        (const float*)d_in[12], (const float*)d_in[13],
        (const float*)d_in[14], (const float*)d_in[15],
        (const float*)d_in[16], (const float*)d_in[17],
        (float*)d_out, B);
}

// Round 12
// 49.868 us; speedup vs baseline: 1.0604x; 1.0604x over previous
//
#include <hip/hip_runtime.h>

typedef float f32x4 __attribute__((ext_vector_type(4)));
typedef __bf16 bf16x8 __attribute__((ext_vector_type(8)));

#define S 32
#define DTC 0.3f

__device__ __forceinline__ float frcp(float x) { return __builtin_amdgcn_rcpf(x); }

// tanh(x) = 1 - 2/(e^{2x}+1); exact saturation via exp->inf/0.
__device__ __forceinline__ float ftanh(float x) {
    float e = __expf(2.0f * x);
    return 1.0f - 2.0f * frcp(e + 1.0f);
}

// jax.nn.gelu(approximate=True)
__device__ __forceinline__ float fgelu(float x) {
    float t = ftanh(0.7978845608028654f * x * (1.0f + 0.044715f * x * x));
    return 0.5f * x * (1.0f + t);
}

// wave-local LDS ordering: drain own DS ops; block compiler reordering.
#define WAVE_LDS_FENCE() asm volatile("s_waitcnt lgkmcnt(0)" ::: "memory")
#define REORDER_FENCE()  asm volatile("" ::: "memory")

union ABFrag { bf16x8 v; };

// load 8 consecutive floats (16B-aligned) as two float4
__device__ __forceinline__ void load_row8(const float* p, float out[8]) {
    const float4* q = reinterpret_cast<const float4*>(p);
    float4 a = q[0], b = q[1];
    out[0]=a.x; out[1]=a.y; out[2]=a.z; out[3]=a.w;
    out[4]=b.x; out[5]=b.y; out[6]=b.z; out[7]=b.w;
}

__device__ __forceinline__ ABFrag pack8(const float f[8]) {
    ABFrag r;
    #pragma unroll
    for (int e = 0; e < 8; e++) r.v[e] = (__bf16)f[e];   // compiler: v_cvt_pk_bf16_f32
    return r;
}

// B-frag: W row-major (K x 32); k = kbase + e (kbase includes 8*lg), fixed col
__device__ __forceinline__ ABFrag load_w(const float* W, int kbase, int col) {
    ABFrag r;
    #pragma unroll
    for (int e = 0; e < 8; e++) r.v[e] = (__bf16)W[(kbase + e) * S + col];
    return r;
}

#define MFMA(a, b, c) __builtin_amdgcn_mfma_f32_16x16x32_bf16((a), (b), (c), 0, 0, 0)

// C-layout (2 n-tiles x 4 rows, fp32) -> A-frag via per-WAVE LDS bounce.
// Per-wave buffer + in-order DS pipe: lgkmcnt(0) before read (RAW),
// reorder fence after read (WAR vs next bounce's writes).
#define BOUNCE(dstFrag, srcC, scale)                                            \
    {                                                                           \
        _Pragma("unroll")                                                       \
        for (int nt_ = 0; nt_ < 2; nt_++)                                       \
            _Pragma("unroll")                                                   \
            for (int r_ = 0; r_ < 4; r_++)                                      \
                lbuf[wid][(4*lg + r_)*40 + lr + 16*nt_] =                       \
                    (__bf16)((srcC)[nt_][r_] * (scale));                        \
        WAVE_LDS_FENCE();                                                       \
        (dstFrag).v = *(const bf16x8*)&lbuf[wid][lr*40 + 8*lg];                 \
        REORDER_FENCE();                                                        \
    }

__global__ __launch_bounds__(256, 2) void moe_kernel(
    const float* __restrict__ cs,  const float* __restrict__ nb,
    const float* __restrict__ Wl,  const float* __restrict__ bl,
    const float* __restrict__ Wm,  const float* __restrict__ bm,
    const float* __restrict__ Wu,  const float* __restrict__ bu,
    const float* __restrict__ Wc,  const float* __restrict__ bc,
    const float* __restrict__ Wd,  const float* __restrict__ bd,
    const float* __restrict__ lng, const float* __restrict__ lnb,
    const float* __restrict__ gW1, const float* __restrict__ gb1,
    const float* __restrict__ gW2, const float* __restrict__ gb2,
    float* __restrict__ out, int B)
{
    __shared__ __align__(16) __bf16 lbuf[4][16 * 40]; // per-wave bounce

    const int tid = threadIdx.x;
    const int wid = tid >> 6, lane = tid & 63;
    const int lr = lane & 15, lg = lane >> 4;
    const int b0 = (blockIdx.x * 4 + wid) * 16;
    if (b0 >= B) return;

    // ---- weight B-frags: 16 frags = 64 VGPRs, held whole kernel
    ABFrag WlB[2][2], WuB[2][2], WdB[2][2], WmB[2], WcB[2];
    #pragma unroll
    for (int nt = 0; nt < 2; nt++) {
        const int col = lr + 16 * nt;
        #pragma unroll
        for (int kt = 0; kt < 2; kt++) {
            WlB[kt][nt] = load_w(Wl, kt * 32 + 8 * lg, col);
            WuB[kt][nt] = load_w(Wu, kt * 32 + 8 * lg, col);
            WdB[kt][nt] = load_w(Wd, kt * 32 + 8 * lg, col);
        }
        WmB[nt] = load_w(Wm, 8 * lg, col);
        WcB[nt] = load_w(Wc, 8 * lg, col);
    }
    // biases in C-layout (per n-tile, col = lr+16nt, same for all 4 rows)
    const float blc[2] = { bl[lr], bl[lr + 16] };
    const float bmc[2] = { bm[lr], bm[lr + 16] };
    const float buc[2] = { bu[lr], bu[lr + 16] };
    const float bcc[2] = { bc[lr], bc[lr + 16] };
    const float bdc[2] = { bd[lr], bd[lr + 16] };

    // ---- x: A-layout (keep fp32 for LN) and C-layout (residuals)
    float xf[8];
    load_row8(cs + (size_t)(b0 + lr) * S + 8 * lg, xf);
    ABFrag xA = pack8(xf);
    float xC[2][4];
    #pragma unroll
    for (int nt = 0; nt < 2; nt++)
        #pragma unroll
        for (int r = 0; r < 4; r++)
            xC[nt][r] = cs[(size_t)(b0 + 4 * lg + r) * S + lr + 16 * nt];

    float act[8];
    #pragma unroll
    for (int e = 0; e < 8; e++) act[e] = 0.0f;

    // ---- local rows 0..2 -> loc (fp32 avg) ; act accum
    float locf[8];
    #pragma unroll
    for (int e = 0; e < 8; e++) locf[e] = 0.0f;
    #pragma unroll
    for (int k = 0; k < 3; k++) {
        float rf[8];
        load_row8(nb + ((size_t)(b0 + lr) * 26 + k) * S + 8 * lg, rf);
        #pragma unroll
        for (int e = 0; e < 8; e++) { locf[e] += rf[e]; act[e] += fabsf(rf[e]); }
    }
    #pragma unroll
    for (int e = 0; e < 8; e++) locf[e] *= (1.0f / 3.0f);
    ABFrag locA = pack8(locf);

    // ---- yl = x + tanh([x,loc]@Wl + bl)   (C-layout)
    float ylC[2][4];
    #pragma unroll
    for (int nt = 0; nt < 2; nt++) {
        f32x4 acc = { blc[nt], blc[nt], blc[nt], blc[nt] };
        acc = MFMA(xA.v,   WlB[0][nt].v, acc);
        acc = MFMA(locA.v, WlB[1][nt].v, acc);
        #pragma unroll
        for (int r = 0; r < 4; r++) ylC[nt][r] = xC[nt][r] + ftanh(acc[r]);
    }

    // ---- func rows 3..16: agg += gelu(row@Wm + bm)   (C-layout accum)
    float aggC[2][4];
    #pragma unroll
    for (int nt = 0; nt < 2; nt++)
        #pragma unroll
        for (int r = 0; r < 4; r++) aggC[nt][r] = 0.0f;
    #pragma unroll 2
    for (int k = 0; k < 14; k++) {
        float rf[8];
        load_row8(nb + ((size_t)(b0 + lr) * 26 + 3 + k) * S + 8 * lg, rf);
        #pragma unroll
        for (int e = 0; e < 8; e++) act[e] += fabsf(rf[e]);
        ABFrag a = pack8(rf);
        #pragma unroll
        for (int nt = 0; nt < 2; nt++) {
            f32x4 am = { bmc[nt], bmc[nt], bmc[nt], bmc[nt] };
            am = MFMA(a.v, WmB[nt].v, am);
            #pragma unroll
            for (int r = 0; r < 4; r++) aggC[nt][r] += fgelu(am[r]);
        }
    }

    // ---- agg/14 -> A-frag (transpose bounce)
    ABFrag aggA;
    BOUNCE(aggA, aggC, (1.0f / 14.0f));

    // ---- h = x + tanh([x,agg]@Wu + bu); yf = h + DT*tanh(h@Wc + bc)
    float hC[2][4], yfC[2][4];
    #pragma unroll
    for (int nt = 0; nt < 2; nt++) {
        f32x4 acc = { buc[nt], buc[nt], buc[nt], buc[nt] };
        acc = MFMA(xA.v,   WuB[0][nt].v, acc);
        acc = MFMA(aggA.v, WuB[1][nt].v, acc);
        #pragma unroll
        for (int r = 0; r < 4; r++) hC[nt][r] = xC[nt][r] + ftanh(acc[r]);
    }
    ABFrag hA;
    BOUNCE(hA, hC, 1.0f);
    #pragma unroll
    for (int nt = 0; nt < 2; nt++) {
        f32x4 acc = { bcc[nt], bcc[nt], bcc[nt], bcc[nt] };
        acc = MFMA(hA.v, WcB[nt].v, acc);
        #pragma unroll
        for (int r = 0; r < 4; r++) yfC[nt][r] = hC[nt][r] + DTC * ftanh(acc[r]);
    }

    // ---- dist rows 17..25 -> fp32 avg ; act accum
    float distf[8];
    #pragma unroll
    for (int e = 0; e < 8; e++) distf[e] = 0.0f;
    #pragma unroll 3
    for (int k = 0; k < 9; k++) {
        float rf[8];
        load_row8(nb + ((size_t)(b0 + lr) * 26 + 17 + k) * S + 8 * lg, rf);
        #pragma unroll
        for (int e = 0; e < 8; e++) { distf[e] += rf[e]; act[e] += fabsf(rf[e]); }
    }
    #pragma unroll
    for (int e = 0; e < 8; e++) distf[e] *= (1.0f / 9.0f);
    ABFrag distA = pack8(distf);

    // ---- gate (fp32, wave reductions over lg groups; vectorized table loads)
    // every lane computes its own row-lr gates; no LDS needed.
    float gate0, gate1, gate2;
    {
        float s = 0.0f;
        #pragma unroll
        for (int e = 0; e < 8; e++) s += xf[e];
        s += __shfl_xor(s, 16); s += __shfl_xor(s, 32);
        const float mu = s * (1.0f / S);
        float v = 0.0f;
        #pragma unroll
        for (int e = 0; e < 8; e++) { float d = xf[e] - mu; v += d * d; }
        v += __shfl_xor(v, 16); v += __shfl_xor(v, 32);
        const float rstd = rsqrtf(v * (1.0f / S) + 1e-5f);

        float lngv[8], lnbv[8];
        load_row8(lng + 8 * lg, lngv);
        load_row8(lnb + 8 * lg, lnbv);

        float g1v[8];
        #pragma unroll
        for (int u = 0; u < 8; u++) g1v[u] = 0.0f;
        #pragma unroll
        for (int e = 0; e < 8; e++) {
            const int i = 8 * lg + e;
            const float a  = (xf[e] - mu) * rstd * lngv[e] + lnbv[e];
            const float ac = act[e] * (1.0f / 26.0f);
            float w1[8], w2[8];
            load_row8(gW1 + i * 8, w1);          // row i of gW1 (8 floats)
            load_row8(gW1 + (S + i) * 8, w2);    // row S+i
            #pragma unroll
            for (int u = 0; u < 8; u++) g1v[u] += a * w1[u] + ac * w2[u];
        }
        float l0 = gb2[0], l1 = gb2[1], l2 = gb2[2];
        #pragma unroll
        for (int u = 0; u < 8; u++) {
            float gt = g1v[u];
            gt += __shfl_xor(gt, 16); gt += __shfl_xor(gt, 32);
            const float g = fgelu(gt + gb1[u]);
            l0 += g * gW2[u * 3 + 0];
            l1 += g * gW2[u * 3 + 1];
            l2 += g * gW2[u * 3 + 2];
        }
        const float mx = fmaxf(l0, fmaxf(l1, l2));
        const float e0 = __expf(l0 - mx), e1 = __expf(l1 - mx), e2 = __expf(l2 - mx);
        const float rs = frcp(e0 + e1 + e2);
        gate0 = e0 * rs; gate1 = e1 * rs; gate2 = e2 * rs;
    }

    // ---- CNF: 3 steps; xt in C-layout + A-frag (re-bounced per step)
    float xtC[2][4];
    #pragma unroll
    for (int nt = 0; nt < 2; nt++)
        #pragma unroll
        for (int r = 0; r < 4; r++) xtC[nt][r] = xC[nt][r];
    ABFrag xtA = xA;
    #pragma unroll 1
    for (int it = 0; it < 3; it++) {
        #pragma unroll
        for (int nt = 0; nt < 2; nt++) {
            f32x4 acc = { bdc[nt], bdc[nt], bdc[nt], bdc[nt] };
            acc = MFMA(xtA.v,  WdB[0][nt].v, acc);
            acc = MFMA(distA.v, WdB[1][nt].v, acc);
            #pragma unroll
            for (int r = 0; r < 4; r++) xtC[nt][r] += DTC * ftanh(acc[r]);
        }
        if (it < 2) { BOUNCE(xtA, xtC, 1.0f); }
    }

    // ---- combine + store (C-layout rows coalesced); gates via wave shuffle:
    // gates for batch row i live in lane i (i<16). row = 4*lg + r.
    #pragma unroll
    for (int nt = 0; nt < 2; nt++)
        #pragma unroll
        for (int r = 0; r < 4; r++) {
            const int srcl = 4 * lg + r;
            const float g0 = __shfl(gate0, srcl);
            const float g1 = __shfl(gate1, srcl);
            const float g2 = __shfl(gate2, srcl);
            out[(size_t)(b0 + 4 * lg + r) * S + lr + 16 * nt] =
                g0 * ylC[nt][r] + g1 * yfC[nt][r] + g2 * xtC[nt][r];
        }
    if (lg == 0) {
        float* gp = out + (size_t)B * S + (size_t)(b0 + lr) * 3;
        gp[0] = gate0; gp[1] = gate1; gp[2] = gate2;
    }
}

extern "C" void kernel_launch(void* const* d_in, const int* in_sizes, int n_in,
                              void* d_out, int out_size, void* d_ws, size_t ws_size,
                              hipStream_t stream)
{
    const int B = in_sizes[0] / S;
    dim3 block(256);
    dim3 grid((B + 63) / 64);   // 64 batch per block (4 waves x 16)
    hipLaunchKernelGGL(moe_kernel, grid, block, 0, stream,
        (const float*)d_in[0],  (const float*)d_in[1],
        (const float*)d_in[2],  (const float*)d_in[3],
        (const float*)d_in[4],  (const float*)d_in[5],
        (const float*)d_in[6],  (const float*)d_in[7],
        (const float*)d_in[8],  (const float*)d_in[9],
        (const float*)d_in[10], (const float*)d_in[11],
        (const float*)d_in[12], (const float*)d_in[13],
        (const float*)d_in[14], (const float*)d_in[15],
        (const float*)d_in[16], (const float*)d_in[17],
        (float*)d_out, B);
}